// Round 2
// baseline (238.884 us; speedup 1.0000x reference)
//
#include <hip/hip_runtime.h>
#include <cstdint>
#include <cstddef>

// Problem constants: B=2, N=16384, K=32, F=64, E=16
#define LOGN 14

typedef __bf16 bf16x8 __attribute__((ext_vector_type(8)));
typedef float f32x4 __attribute__((ext_vector_type(4)));

__device__ __forceinline__ unsigned bf16rne(float f) {
  unsigned u = __builtin_bit_cast(unsigned, f);
  return (u + 0x7fffu + ((u >> 16) & 1u)) >> 16;
}

// wt[m][k] = w[l][m][n] / 32, k = l*16 + n  (bf16), 64x1024 = 128KB
__global__ void prep_wt(const float* __restrict__ w, unsigned short* __restrict__ wt) {
  int idx = blockIdx.x * 256 + threadIdx.x;   // 65536 total
  int m = idx >> 10, k = idx & 1023, l = k >> 4, n = k & 15;
  wt[idx] = (unsigned short)bf16rne(w[l * 1024 + m * 16 + n] * 0.03125f);
}

__device__ __forceinline__ void gather32(const float* __restrict__ nbase,
                                         const int* __restrict__ nl, int lane,
                                         float* __restrict__ sv) {
  #pragma unroll
  for (int j = 0; j < 32; ++j) {
    const int ix = nl[j];                                 // wave-uniform -> s_load
    sv[j] = nbase[((size_t)(unsigned)ix << 6) + lane];    // coalesced 256B gather
  }
}

__device__ __forceinline__ void compute_node(const float4* __restrict__ ep4,
                                             const float* __restrict__ sv,
                                             int lane, int nd,
                                             uint4* __restrict__ g_lds) {
  float G[16];
  #pragma unroll
  for (int n = 0; n < 16; ++n) G[n] = 0.f;
  #pragma unroll
  for (int j = 0; j < 32; ++j) {
    float e[16];
    *(float4*)&e[0]  = ep4[4 * j + 0];    // wave-uniform -> scalar loads
    *(float4*)&e[4]  = ep4[4 * j + 1];
    *(float4*)&e[8]  = ep4[4 * j + 2];
    *(float4*)&e[12] = ep4[4 * j + 3];
    const float s = sv[j];
    #pragma unroll
    for (int n = 0; n < 16; ++n) G[n] = fmaf(s, e[n], G[n]);
  }
  unsigned pk[8];
  #pragma unroll
  for (int h = 0; h < 8; ++h)
    pk[h] = bf16rne(G[2 * h]) | (bf16rne(G[2 * h + 1]) << 16);
  const int nxw = nd & 7;
  uint4* dst = g_lds + nd * 128;
  dst[lane ^ nxw]        = uint4{pk[0], pk[1], pk[2], pk[3]};   // h=0: n 0..7
  dst[64 + (lane ^ nxw)] = uint4{pk[4], pk[5], pk[6], pk[7]};   // h=1: n 8..15
}

// One workgroup = 256 threads (4 waves) = 16 nodes; 32 KB LDS -> 4 blocks/CU.
// Phase A: wave computes G (64l x 16n fp32) for 4 nodes, software-pipelined
//   (gather for node p+1 overlaps FMA loop of node p). LDS chunk c = h*64+l
//   stored at c ^ (node&7) for conflict-friendly b128 access both ways.
// Phase B: wave wid = m-tile; C = 16 nodes x 16 m; 32 K-steps of
//   mfma_f32_16x16x32_bf16, A from LDS, B from wt (L2-resident).
template <bool USE_WT>
__global__ __launch_bounds__(256, 4)
void mp_kernel(const float* __restrict__ nodes, const int* __restrict__ nlist,
               const float* __restrict__ edges, const unsigned short* __restrict__ wt,
               const float* __restrict__ w, float* __restrict__ out) {
  __shared__ uint4 g_lds[16 * 128];   // 32 KB
  const int tid = threadIdx.x;
  const int lane = tid & 63;
  const int wid = __builtin_amdgcn_readfirstlane(tid >> 6);

  // XCD-aware mapping: batch b's nodes slab (4 MB) stays on 4 XCDs' L2.
  const int blk = blockIdx.x;
  const int xcd = blk & 7;
  const int batch = xcd >> 2;
  const int ordinal = ((blk >> 3) << 2) + (xcd & 3);     // [0,1024)
  const int wg0 = (batch << LOGN) + (ordinal << 4);      // flat node base

  const float* __restrict__ nbase = nodes + ((size_t)batch << 20);

  // ---------------- Phase A ----------------
  {
    const size_t gbase = (size_t)wg0 + (wid << 2);
    const int* nl0 = nlist + ((gbase + 0) << 5);
    const int* nl1 = nlist + ((gbase + 1) << 5);
    const int* nl2 = nlist + ((gbase + 2) << 5);
    const int* nl3 = nlist + ((gbase + 3) << 5);
    const float4* ep0 = (const float4*)(edges + ((gbase + 0) << 9));
    const float4* ep1 = (const float4*)(edges + ((gbase + 1) << 9));
    const float4* ep2 = (const float4*)(edges + ((gbase + 2) << 9));
    const float4* ep3 = (const float4*)(edges + ((gbase + 3) << 9));
    const int nd0 = wid << 2;

    float svA[32], svB[32];
    gather32(nbase, nl0, lane, svA);
    gather32(nbase, nl1, lane, svB);
    compute_node(ep0, svA, lane, nd0 + 0, g_lds);
    gather32(nbase, nl2, lane, svA);
    compute_node(ep1, svB, lane, nd0 + 1, g_lds);
    gather32(nbase, nl3, lane, svB);
    compute_node(ep2, svA, lane, nd0 + 2, g_lds);
    compute_node(ep3, svB, lane, nd0 + 3, g_lds);
  }

  __syncthreads();

  // ---------------- Phase B: out = G @ wt^T via MFMA ----------------
  const int col = lane & 15;            // A-row (node) AND D-col (m) index
  const int q   = lane >> 4;
  const int mcol = (wid << 4) + col;    // m in [0,64)
  const int nx = col & 7;
  const int cbase = ((q & 1) << 6) + (q >> 1);   // logical chunk: h*64 + l-off
  const int row0 = col << 7;            // node row base (uint4 units)

  f32x4 acc = {0.f, 0.f, 0.f, 0.f};

  if (USE_WT) {
    const unsigned short* bp = wt + ((size_t)mcol << 10) + (q << 3);
    #pragma unroll 8
    for (int s = 0; s < 32; ++s) {
      const int coff = (cbase + (s << 1)) ^ nx;
      bf16x8 a0 = __builtin_bit_cast(bf16x8, g_lds[row0 + coff]);
      bf16x8 bb = *(const bf16x8*)(bp + (s << 5));
      acc = __builtin_amdgcn_mfma_f32_16x16x32_bf16(a0, bb, acc, 0, 0, 0);
    }
  } else {
    #pragma unroll 4
    for (int s = 0; s < 32; ++s) {
      const int coff = (cbase + (s << 1)) ^ nx;
      bf16x8 a0 = __builtin_bit_cast(bf16x8, g_lds[row0 + coff]);
      const int l = (s << 1) + (q >> 1);
      const float* wp = w + l * 1024 + mcol * 16 + ((q & 1) << 3);
      bf16x8 bb;
      #pragma unroll
      for (int jj = 0; jj < 8; ++jj) bb[jj] = (__bf16)(wp[jj] * 0.03125f);
      acc = __builtin_amdgcn_mfma_f32_16x16x32_bf16(a0, bb, acc, 0, 0, 0);
    }
  }

  // D layout: col = lane&15 (m), row = q*4 + r (node-in-tile)
  #pragma unroll
  for (int r = 0; r < 4; ++r)
    out[((size_t)(wg0 + (q << 2) + r) << 6) + mcol] = acc[r];
}

extern "C" void kernel_launch(void* const* d_in, const int* in_sizes, int n_in,
                              void* d_out, int out_size, void* d_ws, size_t ws_size,
                              hipStream_t stream) {
  const float* nodes = (const float*)d_in[0];
  const int*   nlist = (const int*)d_in[1];
  const float* edges = (const float*)d_in[2];
  const float* w     = (const float*)d_in[3];
  float* out = (float*)d_out;

  if (ws_size >= 131072) {
    unsigned short* wt = (unsigned short*)d_ws;
    prep_wt<<<256, 256, 0, stream>>>(w, wt);
    mp_kernel<true><<<2048, 256, 0, stream>>>(nodes, nlist, edges, wt, w, out);
  } else {
    mp_kernel<false><<<2048, 256, 0, stream>>>(nodes, nlist, edges, nullptr, w, out);
  }
}

// Round 3
// 207.099 us; speedup vs baseline: 1.1535x; 1.1535x over previous
//
#include <hip/hip_runtime.h>
#include <cstdint>
#include <cstddef>

// Problem constants: B=2, N=16384, K=32, F=64, E=16
#define LOGN 14

typedef __bf16 bf16x8 __attribute__((ext_vector_type(8)));
typedef float f32x4 __attribute__((ext_vector_type(4)));

__device__ __forceinline__ unsigned bf16rne(float f) {
  unsigned u = __builtin_bit_cast(unsigned, f);
  return (u + 0x7fffu + ((u >> 16) & 1u)) >> 16;
}

// wt[m][k] = w[l][m][n] / 32, k = l*16 + n  (bf16), 64x1024 = 128KB
__global__ void prep_wt(const float* __restrict__ w, unsigned short* __restrict__ wt) {
  int idx = blockIdx.x * 256 + threadIdx.x;   // 65536 total
  int m = idx >> 10, k = idx & 1023, l = k >> 4, n = k & 15;
  wt[idx] = (unsigned short)bf16rne(w[l * 1024 + m * 16 + n] * 0.03125f);
}

__device__ __forceinline__ void gather32(const float* __restrict__ nbase,
                                         const int* __restrict__ nl, int lane,
                                         float* __restrict__ sv) {
  #pragma unroll
  for (int j = 0; j < 32; ++j) {
    const int ix = nl[j];                                 // wave-uniform -> s_load (grouped)
    sv[j] = nbase[((size_t)(unsigned)ix << 6) + lane];    // coalesced 256B vector gather
  }
}

// FMA loop: e from LDS broadcast (ds_read_b128, in-order lgkmcnt — NO scalar
// loads in this loop), s from registers. Then pack G to bf16 and store to the
// phase-B staging buffer in A-frag chunk order with node-XOR swizzle.
__device__ __forceinline__ void compute_node(const uint4* __restrict__ eb,
                                             const float* __restrict__ sv,
                                             int lane, int nd,
                                             uint4* __restrict__ g_lds) {
  const float4* __restrict__ e4 = (const float4*)eb;
  float G[16];
  #pragma unroll
  for (int n = 0; n < 16; ++n) G[n] = 0.f;
  #pragma unroll
  for (int j = 0; j < 32; ++j) {
    float e[16];
    *(float4*)&e[0]  = e4[4 * j + 0];    // wave-uniform LDS addr -> broadcast, no conflict
    *(float4*)&e[4]  = e4[4 * j + 1];
    *(float4*)&e[8]  = e4[4 * j + 2];
    *(float4*)&e[12] = e4[4 * j + 3];
    const float s = sv[j];
    #pragma unroll
    for (int n = 0; n < 16; ++n) G[n] = fmaf(s, e[n], G[n]);
  }
  unsigned pk[8];
  #pragma unroll
  for (int h = 0; h < 8; ++h)
    pk[h] = bf16rne(G[2 * h]) | (bf16rne(G[2 * h + 1]) << 16);
  const int nxw = nd & 7;
  uint4* dst = g_lds + nd * 128;
  dst[lane ^ nxw]        = uint4{pk[0], pk[1], pk[2], pk[3]};   // h=0: n 0..7
  dst[64 + (lane ^ nxw)] = uint4{pk[4], pk[5], pk[6], pk[7]};   // h=1: n 8..15
}

// One workgroup = 256 threads (4 waves) = 16 nodes.
// LDS: 32 KB G buffer + 16 KB per-wave double-buffered edge staging = 48 KB
//   -> 3 blocks/CU (12 waves). launch_bounds(256,3) -> ~170 VGPR cap so the
//   sv double-buffer + in-flight gathers actually fit in registers (R2's
//   (256,4) throttled to 60 VGPRs and serialized phase A).
// Phase A per wave (4 nodes, software-pipelined, barrier-free staging):
//   edges staged via 2 coalesced global_load_dwordx4 (1 KB each) + 2
//   ds_write_b128 per node; FMA loop consumes via LDS broadcast.
// Phase B: wave wid = m-tile; C = 16 nodes x 16 m; 32 K-steps of
//   mfma_f32_16x16x32_bf16, A from LDS, B from wt (L2-resident).
template <bool USE_WT>
__global__ __launch_bounds__(256, 3)
void mp_kernel(const float* __restrict__ nodes, const int* __restrict__ nlist,
               const float* __restrict__ edges, const unsigned short* __restrict__ wt,
               const float* __restrict__ w, float* __restrict__ out) {
  __shared__ uint4 g_lds[16 * 128];     // 32 KB: G (bf16) in phase-B A-frag order
  __shared__ uint4 ebuf[4][2][128];     // 16 KB: per-wave double-buffered edge stage

  const int tid = threadIdx.x;
  const int lane = tid & 63;
  const int wid = __builtin_amdgcn_readfirstlane(tid >> 6);

  // XCD-aware mapping: batch b's nodes slab (4 MB) stays on 4 XCDs' L2.
  const int blk = blockIdx.x;
  const int xcd = blk & 7;
  const int batch = xcd >> 2;
  const int ordinal = ((blk >> 3) << 2) + (xcd & 3);     // [0,1024)
  const int wg0 = (batch << LOGN) + (ordinal << 4);      // flat node base
  const float* __restrict__ nbase = nodes + ((size_t)batch << 20);

  // ---------------- Phase A ----------------
  {
    const int nd0 = wid << 2;
    const size_t g0 = (size_t)wg0 + nd0;
    uint4* eb0 = &ebuf[wid][0][0];
    uint4* eb1 = &ebuf[wid][1][0];

    float svA[32], svB[32];
    uint4 ta0, ta1, tb0, tb1;

    { const uint4* eg = (const uint4*)(edges + ((g0 + 0) << 9));
      ta0 = eg[lane]; ta1 = eg[64 + lane]; }
    gather32(nbase, nlist + ((g0 + 0) << 5), lane, svA);
    { const uint4* eg = (const uint4*)(edges + ((g0 + 1) << 9));
      tb0 = eg[lane]; tb1 = eg[64 + lane]; }
    gather32(nbase, nlist + ((g0 + 1) << 5), lane, svB);

    eb0[lane] = ta0; eb0[64 + lane] = ta1;                 // ewrite(0)
    compute_node(eb0, svA, lane, nd0 + 0, g_lds);          // node 0

    eb1[lane] = tb0; eb1[64 + lane] = tb1;                 // ewrite(1)
    { const uint4* eg = (const uint4*)(edges + ((g0 + 2) << 9));
      ta0 = eg[lane]; ta1 = eg[64 + lane]; }               // eload(2)
    gather32(nbase, nlist + ((g0 + 2) << 5), lane, svA);   // gather(2)
    compute_node(eb1, svB, lane, nd0 + 1, g_lds);          // node 1

    eb0[lane] = ta0; eb0[64 + lane] = ta1;                 // ewrite(2)
    { const uint4* eg = (const uint4*)(edges + ((g0 + 3) << 9));
      tb0 = eg[lane]; tb1 = eg[64 + lane]; }               // eload(3)
    gather32(nbase, nlist + ((g0 + 3) << 5), lane, svB);   // gather(3)
    compute_node(eb0, svA, lane, nd0 + 2, g_lds);          // node 2

    eb1[lane] = tb0; eb1[64 + lane] = tb1;                 // ewrite(3)
    compute_node(eb1, svB, lane, nd0 + 3, g_lds);          // node 3
  }

  __syncthreads();

  // ---------------- Phase B: out = G @ wt^T via MFMA ----------------
  const int col = lane & 15;            // A-row (node) AND D-col (m) index
  const int q   = lane >> 4;
  const int mcol = (wid << 4) + col;    // m in [0,64)
  const int nx = col & 7;
  const int cbase = ((q & 1) << 6) + (q >> 1);   // logical chunk: h*64 + l-off
  const int row0 = col << 7;            // node row base (uint4 units)

  f32x4 acc = {0.f, 0.f, 0.f, 0.f};

  if (USE_WT) {
    const unsigned short* bp = wt + ((size_t)mcol << 10) + (q << 3);
    #pragma unroll 8
    for (int s = 0; s < 32; ++s) {
      const int coff = (cbase + (s << 1)) ^ nx;
      bf16x8 a0 = __builtin_bit_cast(bf16x8, g_lds[row0 + coff]);
      bf16x8 bb = *(const bf16x8*)(bp + (s << 5));
      acc = __builtin_amdgcn_mfma_f32_16x16x32_bf16(a0, bb, acc, 0, 0, 0);
    }
  } else {
    #pragma unroll 4
    for (int s = 0; s < 32; ++s) {
      const int coff = (cbase + (s << 1)) ^ nx;
      bf16x8 a0 = __builtin_bit_cast(bf16x8, g_lds[row0 + coff]);
      const int l = (s << 1) + (q >> 1);
      const float* wp = w + l * 1024 + mcol * 16 + ((q & 1) << 3);
      bf16x8 bb;
      #pragma unroll
      for (int jj = 0; jj < 8; ++jj) bb[jj] = (__bf16)(wp[jj] * 0.03125f);
      acc = __builtin_amdgcn_mfma_f32_16x16x32_bf16(a0, bb, acc, 0, 0, 0);
    }
  }

  // D layout: col = lane&15 (m), row = q*4 + r (node-in-tile)
  #pragma unroll
  for (int r = 0; r < 4; ++r)
    out[((size_t)(wg0 + (q << 2) + r) << 6) + mcol] = acc[r];
}

extern "C" void kernel_launch(void* const* d_in, const int* in_sizes, int n_in,
                              void* d_out, int out_size, void* d_ws, size_t ws_size,
                              hipStream_t stream) {
  const float* nodes = (const float*)d_in[0];
  const int*   nlist = (const int*)d_in[1];
  const float* edges = (const float*)d_in[2];
  const float* w     = (const float*)d_in[3];
  float* out = (float*)d_out;

  if (ws_size >= 131072) {
    unsigned short* wt = (unsigned short*)d_ws;
    prep_wt<<<256, 256, 0, stream>>>(w, wt);
    mp_kernel<true><<<2048, 256, 0, stream>>>(nodes, nlist, edges, wt, w, out);
  } else {
    mp_kernel<false><<<2048, 256, 0, stream>>>(nodes, nlist, edges, nullptr, w, out);
  }
}